// Round 1
// baseline (6002.775 us; speedup 1.0000x reference)
//
#include <hip/hip_runtime.h>
#include <math.h>

#define BATCH   2097152
#define GRID    2048
#define BLOCK   256
#define NREP    16          // stats replicas to spread atomic contention
#define NSETS   8           // 0:h0, 1:r1_0, 2:h1, 3:r1_1, 4:h2, 5:r1_2, 6:h3, 7:r1_3

__device__ __forceinline__ float silu_f(float x) {
    // x * sigmoid(x); rcp is ~1 ulp, exp ~2 ulp -- plenty for the 0.345 abs threshold
    return x * __builtin_amdgcn_rcpf(1.0f + __expf(-x));
}

// ---- per-block stats reduction: 64 fp32 accs -> wave shuffle -> LDS -> fp64 atomic ----
__device__ __forceinline__ void block_stats_reduce(
    const float* stS, const float* stQ, float (*sRed)[64], double* sOut, int tid)
{
    const int lane = tid & 63, wid = tid >> 6;
    #pragma unroll
    for (int c = 0; c < 32; ++c) {
        float v1 = stS[c], v2 = stQ[c];
        #pragma unroll
        for (int off = 32; off > 0; off >>= 1) {
            v1 += __shfl_down(v1, off, 64);
            v2 += __shfl_down(v2, off, 64);
        }
        if (lane == 0) { sRed[wid][c] = v1; sRed[wid][32 + c] = v2; }
    }
    __syncthreads();
    if (tid < 64) {
        float tot = sRed[0][tid] + sRed[1][tid] + sRed[2][tid] + sRed[3][tid];
        atomicAdd(sOut + tid, (double)tot);
    }
}

// ---- Fold rfft -> complex mix -> irfft into one real 32x32 matrix per layer (+I skip) ----
__global__ void setup_f_kernel(const float* __restrict__ wr, const float* __restrict__ wi,
                               float* __restrict__ Fp)
{
    __shared__ double cs[32], sn[32];
    const int l = blockIdx.x, tid = threadIdx.x;
    if (tid < 32) {
        double a = (2.0 * 3.14159265358979323846 / 32.0) * (double)tid;
        cs[tid] = cos(a); sn[tid] = sin(a);
    }
    __syncthreads();
    const float* wrl = wr + l * 289;
    const float* wil = wi + l * 289;
    for (int p = tid; p < 1024; p += BLOCK) {
        const int d = p >> 5, j = p & 31;
        double acc = 0.0;
        for (int m = 0; m < 17; ++m) {
            double yr = 0.0, yi = 0.0;
            for (int k = 0; k < 17; ++k) {
                const double c = cs[(k * d) & 31], s = sn[(k * d) & 31];
                const double a = (double)wrl[k * 17 + m], b = (double)wil[k * 17 + m];
                yr += c * a + s * b;   // coeff of h[d] in Re(y[m])
                yi += c * b - s * a;   // coeff of h[d] in Im(y[m])
            }
            const double alpha = (m == 0 || m == 16) ? 1.0 : 2.0;
            acc += alpha * (cs[(j * m) & 31] * yr - sn[(j * m) & 31] * yi);
        }
        const double F = acc * (1.0 / 32.0);
        Fp[l * 1024 + d * 32 + j] = (float)(F + ((d == j) ? 1.0 : 0.0));
    }
}

// ---- stem: h = x @ stem_w + stem_b ; accumulate stats(h) for bn1 of layer 0 ----
__global__ __launch_bounds__(BLOCK, 2) void stem_kernel(
    const float* __restrict__ x, const float* __restrict__ sw, const float* __restrict__ sb,
    float* __restrict__ h, double* __restrict__ sOut)
{
    __shared__ float sSB[32];
    __shared__ float sRed[4][64];
    const int tid = threadIdx.x;
    if (tid < 32) sSB[tid] = sb[tid];
    __syncthreads();
    float stS[32], stQ[32];
    #pragma unroll
    for (int c = 0; c < 32; ++c) { stS[c] = 0.f; stQ[c] = 0.f; }
    const float4* swv = (const float4*)sw;
    for (int row = blockIdx.x * BLOCK + tid; row < BATCH; row += GRID * BLOCK) {
        const float2* xp = (const float2*)(x + (size_t)row * 10);
        float xv[10];
        #pragma unroll
        for (int k = 0; k < 5; ++k) { float2 v = xp[k]; xv[2*k] = v.x; xv[2*k+1] = v.y; }
        float acc[32];
        #pragma unroll
        for (int c = 0; c < 32; ++c) acc[c] = 0.f;
        #pragma unroll
        for (int k = 0; k < 10; ++k) {
            const float xk = xv[k];
            #pragma unroll
            for (int c8 = 0; c8 < 8; ++c8) {
                const float4 w = swv[k * 8 + c8];
                acc[4*c8]   += xk * w.x; acc[4*c8+1] += xk * w.y;
                acc[4*c8+2] += xk * w.z; acc[4*c8+3] += xk * w.w;
            }
        }
        float4* op = (float4*)(h + (size_t)row * 32);
        #pragma unroll
        for (int j = 0; j < 8; ++j) {
            float4 v;
            v.x = acc[4*j]   + sSB[4*j];
            v.y = acc[4*j+1] + sSB[4*j+1];
            v.z = acc[4*j+2] + sSB[4*j+2];
            v.w = acc[4*j+3] + sSB[4*j+3];
            op[j] = v;
            stS[4*j]   += v.x; stQ[4*j]   += v.x * v.x;
            stS[4*j+1] += v.y; stQ[4*j+1] += v.y * v.y;
            stS[4*j+2] += v.z; stQ[4*j+2] += v.z * v.z;
            stS[4*j+3] += v.w; stQ[4*j+3] += v.w * v.w;
        }
    }
    block_stats_reduce(stS, stQ, sRed, sOut + (size_t)(blockIdx.x & (NREP - 1)) * 64, tid);
}

// ---- P1: stats of r1 = silu(bn1(h)) @ W1 + b1 (nothing written to HBM but stats) ----
__global__ __launch_bounds__(BLOCK, 2) void p1_kernel(
    const float* __restrict__ h_in,
    const double* __restrict__ sIn, double* __restrict__ sOut,
    const float* __restrict__ g1v, const float* __restrict__ b1v,
    const float* __restrict__ w1, const float* __restrict__ lb1)
{
    __shared__ float sA1[32], sC1[32], sLB[32];
    __shared__ float sRed[4][64];
    const int tid = threadIdx.x;
    if (tid < 32) {
        double s = 0, q = 0;
        #pragma unroll
        for (int r = 0; r < NREP; ++r) { s += sIn[r*64 + tid]; q += sIn[r*64 + 32 + tid]; }
        const double inv = 1.0 / (double)BATCH;
        const double mu = s * inv, var = q * inv - mu * mu;
        const float a = (float)(1.0 / sqrt(var + 1e-5)) * g1v[tid];
        sA1[tid] = a; sC1[tid] = b1v[tid] - (float)mu * a; sLB[tid] = lb1[tid];
    }
    __syncthreads();
    float stS[32], stQ[32];
    #pragma unroll
    for (int c = 0; c < 32; ++c) { stS[c] = 0.f; stQ[c] = 0.f; }
    const float4* w1v4 = (const float4*)w1;
    for (int row = blockIdx.x * BLOCK + tid; row < BATCH; row += GRID * BLOCK) {
        const float4* hp = (const float4*)(h_in + (size_t)row * 32);
        float h[32];
        #pragma unroll
        for (int j = 0; j < 8; ++j) { float4 v = hp[j]; h[4*j]=v.x; h[4*j+1]=v.y; h[4*j+2]=v.z; h[4*j+3]=v.w; }
        float t[32];
        #pragma unroll
        for (int d = 0; d < 32; ++d) t[d] = silu_f(sA1[d] * h[d] + sC1[d]);
        float acc[32];
        #pragma unroll
        for (int c = 0; c < 32; ++c) acc[c] = 0.f;
        #pragma unroll
        for (int d = 0; d < 32; ++d) {
            const float td = t[d];
            #pragma unroll
            for (int c8 = 0; c8 < 8; ++c8) {
                const float4 w = w1v4[d * 8 + c8];
                acc[4*c8]   += td * w.x; acc[4*c8+1] += td * w.y;
                acc[4*c8+2] += td * w.z; acc[4*c8+3] += td * w.w;
            }
        }
        #pragma unroll
        for (int c = 0; c < 32; ++c) {
            const float r = acc[c] + sLB[c];
            stS[c] += r; stQ[c] += r * r;
        }
    }
    block_stats_reduce(stS, stQ, sRed, sOut + (size_t)(blockIdx.x & (NREP - 1)) * 64, tid);
}

// ---- P2: full layer: h_new = silu(h@Fp + silu(bn2(r1))@W2 + b2); stats(h_new) or head ----
template<bool LAST>
__global__ __launch_bounds__(BLOCK, 2) void p2_kernel(
    const float* __restrict__ h_in, float* __restrict__ h_out, float* __restrict__ out,
    const double* __restrict__ sIn1, const double* __restrict__ sIn2, double* __restrict__ sOut,
    const float* __restrict__ g1v, const float* __restrict__ b1v,
    const float* __restrict__ w1, const float* __restrict__ lb1,
    const float* __restrict__ g2v, const float* __restrict__ b2v,
    const float* __restrict__ w2, const float* __restrict__ lb2,
    const float* __restrict__ Fp,
    const float* __restrict__ hw, const float* __restrict__ hb)
{
    __shared__ float sA1[32], sC1[32], sA2[32], sD2[32], sB2[32];
    __shared__ float sRed[4][64];
    const int tid = threadIdx.x;
    if (tid < 32) {
        double s = 0, q = 0;
        #pragma unroll
        for (int r = 0; r < NREP; ++r) { s += sIn1[r*64 + tid]; q += sIn1[r*64 + 32 + tid]; }
        const double inv = 1.0 / (double)BATCH;
        const double mu = s * inv, var = q * inv - mu * mu;
        const float a = (float)(1.0 / sqrt(var + 1e-5)) * g1v[tid];
        sA1[tid] = a; sC1[tid] = b1v[tid] - (float)mu * a;
        sB2[tid] = lb2[tid];
    } else if (tid < 64) {
        const int c = tid - 32;
        double s = 0, q = 0;
        #pragma unroll
        for (int r = 0; r < NREP; ++r) { s += sIn2[r*64 + c]; q += sIn2[r*64 + 32 + c]; }
        const double inv = 1.0 / (double)BATCH;
        const double mu = s * inv, var = q * inv - mu * mu;
        const float a = (float)(1.0 / sqrt(var + 1e-5)) * g2v[c];
        // u = silu(a2*(t@W1 + lb1) + (b2 - mu*a2)) = silu(a2*acc + d2)
        sA2[c] = a; sD2[c] = a * lb1[c] + b2v[c] - (float)mu * a;
    }
    __syncthreads();

    float stS[32], stQ[32];
    if (!LAST) {
        #pragma unroll
        for (int c = 0; c < 32; ++c) { stS[c] = 0.f; stQ[c] = 0.f; }
    }
    const float4* w1v4 = (const float4*)w1;
    const float4* w2v4 = (const float4*)w2;
    const float4* fp4  = (const float4*)Fp;

    for (int row = blockIdx.x * BLOCK + tid; row < BATCH; row += GRID * BLOCK) {
        const float4* hp = (const float4*)(h_in + (size_t)row * 32);
        float h[32];
        #pragma unroll
        for (int j = 0; j < 8; ++j) { float4 v = hp[j]; h[4*j]=v.x; h[4*j+1]=v.y; h[4*j+2]=v.z; h[4*j+3]=v.w; }
        float t[32];
        #pragma unroll
        for (int d = 0; d < 32; ++d) t[d] = silu_f(sA1[d] * h[d] + sC1[d]);
        float acc[32];
        #pragma unroll
        for (int c = 0; c < 32; ++c) acc[c] = 0.f;
        #pragma unroll
        for (int d = 0; d < 32; ++d) {
            const float td = t[d];
            #pragma unroll
            for (int c8 = 0; c8 < 8; ++c8) {
                const float4 w = w1v4[d * 8 + c8];
                acc[4*c8]   += td * w.x; acc[4*c8+1] += td * w.y;
                acc[4*c8+2] += td * w.z; acc[4*c8+3] += td * w.w;
            }
        }
        float u[32];
        #pragma unroll
        for (int c = 0; c < 32; ++c) u[c] = silu_f(sA2[c] * acc[c] + sD2[c]);
        float acc2[32];
        #pragma unroll
        for (int c = 0; c < 32; ++c) acc2[c] = sB2[c];
        #pragma unroll
        for (int d = 0; d < 32; ++d) {
            const float ud = u[d], hd = h[d];
            #pragma unroll
            for (int c8 = 0; c8 < 8; ++c8) {
                const float4 wa = w2v4[d * 8 + c8];
                const float4 wf = fp4[d * 8 + c8];
                acc2[4*c8]   += ud * wa.x + hd * wf.x;
                acc2[4*c8+1] += ud * wa.y + hd * wf.y;
                acc2[4*c8+2] += ud * wa.z + hd * wf.z;
                acc2[4*c8+3] += ud * wa.w + hd * wf.w;
            }
        }
        float hn[32];
        #pragma unroll
        for (int c = 0; c < 32; ++c) hn[c] = silu_f(acc2[c]);
        if (!LAST) {
            float4* op = (float4*)(h_out + (size_t)row * 32);
            #pragma unroll
            for (int j = 0; j < 8; ++j) {
                float4 v;
                v.x = hn[4*j]; v.y = hn[4*j+1]; v.z = hn[4*j+2]; v.w = hn[4*j+3];
                op[j] = v;
            }
            #pragma unroll
            for (int c = 0; c < 32; ++c) { stS[c] += hn[c]; stQ[c] += hn[c] * hn[c]; }
        } else {
            float o[10];
            #pragma unroll
            for (int k = 0; k < 10; ++k) o[k] = hb[k];
            #pragma unroll
            for (int d = 0; d < 32; ++d) {
                const float hd = hn[d];
                #pragma unroll
                for (int k = 0; k < 10; ++k) o[k] += hd * hw[d * 10 + k];
            }
            float2* op = (float2*)(out + (size_t)row * 10);
            #pragma unroll
            for (int k = 0; k < 5; ++k) { float2 v; v.x = o[2*k]; v.y = o[2*k+1]; op[k] = v; }
        }
    }
    if (!LAST) {
        block_stats_reduce(stS, stQ, sRed, sOut + (size_t)(blockIdx.x & (NREP - 1)) * 64, tid);
    }
}

extern "C" void kernel_launch(void* const* d_in, const int* in_sizes, int n_in,
                              void* d_out, int out_size, void* d_ws, size_t ws_size,
                              hipStream_t stream)
{
    const float* x      = (const float*)d_in[0];
    const float* stem_w = (const float*)d_in[1];
    const float* stem_b = (const float*)d_in[2];
    const float* fno_wr = (const float*)d_in[3];
    const float* fno_wi = (const float*)d_in[4];
    const float* bn1_g  = (const float*)d_in[5];
    const float* bn1_b  = (const float*)d_in[6];
    const float* lin1_w = (const float*)d_in[7];
    const float* lin1_b = (const float*)d_in[8];
    const float* bn2_g  = (const float*)d_in[9];
    const float* bn2_b  = (const float*)d_in[10];
    const float* lin2_w = (const float*)d_in[11];
    const float* lin2_b = (const float*)d_in[12];
    const float* head_w = (const float*)d_in[13];
    const float* head_b = (const float*)d_in[14];

    // workspace: [ h (B*32 f32) | Fp (4*32*32 f32) | stats (8 sets * 16 reps * 64 f64) ]
    float*  h  = (float*)d_ws;
    float*  Fp = (float*)((char*)d_ws + (size_t)BATCH * 32 * sizeof(float));
    double* st = (double*)((char*)d_ws + (size_t)BATCH * 32 * sizeof(float) + 16384);

    hipMemsetAsync(st, 0, (size_t)NSETS * NREP * 64 * sizeof(double), stream);
    setup_f_kernel<<<4, BLOCK, 0, stream>>>(fno_wr, fno_wi, Fp);
    stem_kernel<<<GRID, BLOCK, 0, stream>>>(x, stem_w, stem_b, h, st);

    for (int l = 0; l < 4; ++l) {
        double* sH = st + (size_t)(2 * l) * NREP * 64;       // stats of h_l
        double* sR = st + (size_t)(2 * l + 1) * NREP * 64;   // stats of r1_l
        p1_kernel<<<GRID, BLOCK, 0, stream>>>(
            h, sH, sR,
            bn1_g + l * 32, bn1_b + l * 32, lin1_w + l * 1024, lin1_b + l * 32);
        if (l < 3) {
            double* sN = st + (size_t)(2 * l + 2) * NREP * 64;
            p2_kernel<false><<<GRID, BLOCK, 0, stream>>>(
                h, h, nullptr, sH, sR, sN,
                bn1_g + l * 32, bn1_b + l * 32, lin1_w + l * 1024, lin1_b + l * 32,
                bn2_g + l * 32, bn2_b + l * 32, lin2_w + l * 1024, lin2_b + l * 32,
                Fp + l * 1024, nullptr, nullptr);
        } else {
            p2_kernel<true><<<GRID, BLOCK, 0, stream>>>(
                h, nullptr, (float*)d_out, sH, sR, nullptr,
                bn1_g + l * 32, bn1_b + l * 32, lin1_w + l * 1024, lin1_b + l * 32,
                bn2_g + l * 32, bn2_b + l * 32, lin2_w + l * 1024, lin2_b + l * 32,
                Fp + l * 1024, head_w, head_b);
        }
    }
}

// Round 2
// 679.019 us; speedup vs baseline: 8.8404x; 8.8404x over previous
//
#include <hip/hip_runtime.h>
#include <math.h>

#define BATCH   2097152
#define NTILES  (BATCH / 16)
#define GRID    2048
#define BLOCK   256
#define WAVES   (GRID * (BLOCK / 64))
#define NREP    16
#define NSETS   8

typedef __attribute__((ext_vector_type(8))) short short8;   // 8 bf16 = 4 VGPRs (MFMA A/B frag)
typedef __attribute__((ext_vector_type(4))) float f32x4;    // MFMA C/D frag
typedef unsigned short ushort_t;

__device__ __forceinline__ float silu_f(float x) {
    return x * __builtin_amdgcn_rcpf(1.0f + __expf(-x));
}
__device__ __forceinline__ unsigned short f2bf(float f) {   // fp32 -> bf16 RTNE
    union { float f; unsigned u; } v; v.f = f;
    unsigned r = v.u + 0x7fffu + ((v.u >> 16) & 1u);
    return (unsigned short)(r >> 16);
}
__device__ __forceinline__ float bf2f(unsigned short b) {
    union { unsigned u; float f; } v; v.u = ((unsigned)b) << 16;
    return v.f;
}
__device__ __forceinline__ short8 pack8(const float* f) {
    short8 r;
    #pragma unroll
    for (int j = 0; j < 8; ++j) ((unsigned short*)&r)[j] = f2bf(f[j]);
    return r;
}
__device__ __forceinline__ f32x4 mfma16(short8 a, short8 b, f32x4 c) {
    return __builtin_amdgcn_mfma_f32_16x16x32_bf16(a, b, c, 0, 0, 0);
}
// B fragment: lane holds B[k0+j][n], k0=(lane>>4)*8, n=(lane&15)+16*half. W row-major [K][ldN].
__device__ __forceinline__ short8 wfrag(const float* W, int ldN, int K, int lane, int half, int N) {
    short8 r;
    const int n = (lane & 15) + 16 * half;
    const int k0 = (lane >> 4) * 8;
    #pragma unroll
    for (int j = 0; j < 8; ++j) {
        const int k = k0 + j;
        const float v = (k < K && n < N) ? W[k * ldN + n] : 0.f;
        ((unsigned short*)&r)[j] = f2bf(v);
    }
    return r;
}
// BN folded coefs from replicated fp64 sums: y = A*x + C
__device__ __forceinline__ void bn_coef(const double* sIn, const float* g, const float* b,
                                        int c, float* A, float* C) {
    double s = 0, q = 0;
    #pragma unroll
    for (int r = 0; r < NREP; ++r) { s += sIn[r * 64 + c]; q += sIn[r * 64 + 32 + c]; }
    const double inv = 1.0 / (double)BATCH;
    const double mu = s * inv, var = q * inv - mu * mu;
    const float a = (float)(1.0 / sqrt(var + 1e-5)) * g[c];
    *A = a; *C = b[c] - (float)mu * a;
}
// C-layout stats: lane holds channels (lane&15) and (lane&15)+16
__device__ __forceinline__ void stats_reduce_c(float sS0, float sQ0, float sS1, float sQ1,
                                               float (*sRed)[64], double* sOut, int tid) {
    const int lane = tid & 63, wid = tid >> 6;
    sS0 += __shfl_down(sS0, 32); sS0 += __shfl_down(sS0, 16);
    sQ0 += __shfl_down(sQ0, 32); sQ0 += __shfl_down(sQ0, 16);
    sS1 += __shfl_down(sS1, 32); sS1 += __shfl_down(sS1, 16);
    sQ1 += __shfl_down(sQ1, 32); sQ1 += __shfl_down(sQ1, 16);
    if (lane < 16) {
        sRed[wid][lane] = sS0; sRed[wid][16 + lane] = sS1;
        sRed[wid][32 + lane] = sQ0; sRed[wid][48 + lane] = sQ1;
    }
    __syncthreads();
    if (tid < 64) {
        const float tot = sRed[0][tid] + sRed[1][tid] + sRed[2][tid] + sRed[3][tid];
        atomicAdd(sOut + tid, (double)tot);
    }
}

// ---- Fold rfft -> complex mix -> irfft into one real 32x32 matrix per layer (+I skip) ----
__global__ void setup_f_kernel(const float* __restrict__ wr, const float* __restrict__ wi,
                               float* __restrict__ Fp)
{
    __shared__ double cs[32], sn[32];
    const int l = blockIdx.x, tid = threadIdx.x;
    if (tid < 32) {
        double a = (2.0 * 3.14159265358979323846 / 32.0) * (double)tid;
        cs[tid] = cos(a); sn[tid] = sin(a);
    }
    __syncthreads();
    const float* wrl = wr + l * 289;
    const float* wil = wi + l * 289;
    for (int p = tid; p < 1024; p += BLOCK) {
        const int d = p >> 5, j = p & 31;
        double acc = 0.0;
        for (int m = 0; m < 17; ++m) {
            double yr = 0.0, yi = 0.0;
            for (int k = 0; k < 17; ++k) {
                const double c = cs[(k * d) & 31], s = sn[(k * d) & 31];
                const double a = (double)wrl[k * 17 + m], b = (double)wil[k * 17 + m];
                yr += c * a + s * b;
                yi += c * b - s * a;
            }
            const double alpha = (m == 0 || m == 16) ? 1.0 : 2.0;
            acc += alpha * (cs[(j * m) & 31] * yr - sn[(j * m) & 31] * yi);
        }
        const double F = acc * (1.0 / 32.0);
        Fp[l * 1024 + d * 32 + j] = (float)(F + ((d == j) ? 1.0 : 0.0));
    }
}

// ---- stem: h = x @ stem_w + stem_b (MFMA, K=10 zero-padded); h stored bf16; stats(h) ----
__global__ __launch_bounds__(BLOCK) void stem_kernel(
    const float* __restrict__ x, const float* __restrict__ sw, const float* __restrict__ sb,
    ushort_t* __restrict__ h, double* __restrict__ sOut)
{
    __shared__ ushort_t tile[4][512] __attribute__((aligned(16)));
    __shared__ float sRed[4][64];
    const int tid = threadIdx.x, lane = tid & 63, wid = tid >> 6;
    const int m = lane & 15, q = lane >> 4;
    const short8 B0 = wfrag(sw, 32, 10, lane, 0, 32);
    const short8 B1 = wfrag(sw, 32, 10, lane, 1, 32);
    const float bc0 = sb[m], bc1 = sb[m + 16];
    float sS0 = 0, sQ0 = 0, sS1 = 0, sQ1 = 0;
    ushort_t* myT = tile[wid];
    for (int t = blockIdx.x * (BLOCK / 64) + wid; t < NTILES; t += WAVES) {
        const size_t rb = (size_t)t * 16;
        float xv[8];
        #pragma unroll
        for (int j2 = 0; j2 < 4; ++j2) {
            const int k = q * 8 + j2 * 2;
            if (k < 10) {
                const float2 v = *(const float2*)(x + (rb + m) * 10 + k);
                xv[2 * j2] = v.x; xv[2 * j2 + 1] = v.y;
            } else { xv[2 * j2] = 0.f; xv[2 * j2 + 1] = 0.f; }
        }
        const short8 xa = pack8(xv);
        f32x4 a0 = {bc0, bc0, bc0, bc0}, a1 = {bc1, bc1, bc1, bc1};
        a0 = mfma16(xa, B0, a0);
        a1 = mfma16(xa, B1, a1);
        __builtin_amdgcn_wave_barrier();
        #pragma unroll
        for (int r = 0; r < 4; ++r) {
            sS0 += a0[r]; sQ0 += a0[r] * a0[r];
            sS1 += a1[r]; sQ1 += a1[r] * a1[r];
            myT[(q * 4 + r) * 32 + m]      = f2bf(a0[r]);
            myT[(q * 4 + r) * 32 + m + 16] = f2bf(a1[r]);
        }
        __builtin_amdgcn_wave_barrier();
        const short8 hv = *(const short8*)(myT + lane * 8);   // coalesced row-major tile
        *(short8*)(h + rb * 32 + lane * 8) = hv;
        __builtin_amdgcn_wave_barrier();
    }
    stats_reduce_c(sS0, sQ0, sS1, sQ1, sRed, sOut + (size_t)(blockIdx.x & (NREP - 1)) * 64, tid);
}

// ---- P1: stats of r1 = silu(bn1(h)) @ W1 + lb1 ----
__global__ __launch_bounds__(BLOCK) void p1_kernel(
    const ushort_t* __restrict__ h_in, const double* __restrict__ sIn, double* __restrict__ sOut,
    const float* __restrict__ g1, const float* __restrict__ b1,
    const float* __restrict__ w1, const float* __restrict__ lb1)
{
    __shared__ float cA[32], cC[32];
    __shared__ float sRed[4][64];
    const int tid = threadIdx.x, lane = tid & 63, wid = tid >> 6;
    if (tid < 32) bn_coef(sIn, g1, b1, tid, &cA[tid], &cC[tid]);
    __syncthreads();
    const int m = lane & 15, q = lane >> 4;
    float a1k[8], c1k[8];
    #pragma unroll
    for (int j = 0; j < 8; ++j) { a1k[j] = cA[q * 8 + j]; c1k[j] = cC[q * 8 + j]; }
    const short8 W10 = wfrag(w1, 32, 32, lane, 0, 32);
    const short8 W11 = wfrag(w1, 32, 32, lane, 1, 32);
    const float lbc0 = lb1[m], lbc1 = lb1[m + 16];
    float sS0 = 0, sQ0 = 0, sS1 = 0, sQ1 = 0;
    for (int t = blockIdx.x * (BLOCK / 64) + wid; t < NTILES; t += WAVES) {
        const size_t rb = (size_t)t * 16;
        const short8 ha = *(const short8*)(h_in + (rb + m) * 32 + q * 8);
        float tf[8];
        #pragma unroll
        for (int j = 0; j < 8; ++j)
            tf[j] = silu_f(a1k[j] * bf2f(((const unsigned short*)&ha)[j]) + c1k[j]);
        const short8 ta = pack8(tf);
        f32x4 r0 = {lbc0, lbc0, lbc0, lbc0}, r1 = {lbc1, lbc1, lbc1, lbc1};
        r0 = mfma16(ta, W10, r0);
        r1 = mfma16(ta, W11, r1);
        #pragma unroll
        for (int r = 0; r < 4; ++r) {
            sS0 += r0[r]; sQ0 += r0[r] * r0[r];
            sS1 += r1[r]; sQ1 += r1[r] * r1[r];
        }
    }
    stats_reduce_c(sS0, sQ0, sS1, sQ1, sRed, sOut + (size_t)(blockIdx.x & (NREP - 1)) * 64, tid);
}

// ---- P2: h_new = silu(h@Fp + silu(bn2(t@W1+lb1))@W2 + lb2); stats(h_new) or head ----
template<bool LAST>
__global__ __launch_bounds__(BLOCK) void p2_kernel(
    const ushort_t* __restrict__ h_in, ushort_t* __restrict__ h_out, float* __restrict__ out,
    const double* __restrict__ sIn1, const double* __restrict__ sIn2, double* __restrict__ sOut,
    const float* __restrict__ g1, const float* __restrict__ b1,
    const float* __restrict__ w1, const float* __restrict__ lb1,
    const float* __restrict__ g2, const float* __restrict__ b2,
    const float* __restrict__ w2, const float* __restrict__ lb2,
    const float* __restrict__ Fp, const float* __restrict__ hw, const float* __restrict__ hb)
{
    __shared__ float cA1[32], cC1[32], cA2[32], cD2[32];
    __shared__ ushort_t tile[4][512] __attribute__((aligned(16)));
    __shared__ float sRed[4][64];
    const int tid = threadIdx.x, lane = tid & 63, wid = tid >> 6;
    if (tid < 32) {
        bn_coef(sIn1, g1, b1, tid, &cA1[tid], &cC1[tid]);
    } else if (tid < 64) {
        const int c = tid - 32;
        float A, C;
        bn_coef(sIn2, g2, b2, c, &A, &C);
        cA2[c] = A; cD2[c] = C + A * lb1[c];   // fold lb1 into bn2 offset
    }
    __syncthreads();
    const int m = lane & 15, q = lane >> 4;
    float a1k[8], c1k[8];
    #pragma unroll
    for (int j = 0; j < 8; ++j) { a1k[j] = cA1[q * 8 + j]; c1k[j] = cC1[q * 8 + j]; }
    const float a2c0 = cA2[m], d2c0 = cD2[m], a2c1 = cA2[m + 16], d2c1 = cD2[m + 16];
    const float b2c0 = lb2[m], b2c1 = lb2[m + 16];
    const short8 W10 = wfrag(w1, 32, 32, lane, 0, 32);
    const short8 W11 = wfrag(w1, 32, 32, lane, 1, 32);
    const short8 W20 = wfrag(w2, 32, 32, lane, 0, 32);
    const short8 W21 = wfrag(w2, 32, 32, lane, 1, 32);
    const short8 F0  = wfrag(Fp, 32, 32, lane, 0, 32);
    const short8 F1  = wfrag(Fp, 32, 32, lane, 1, 32);
    short8 HW = {};
    float hbc = 0.f;
    if (LAST) { HW = wfrag(hw, 10, 32, lane, 0, 10); hbc = (m < 10) ? hb[m] : 0.f; }
    float sS0 = 0, sQ0 = 0, sS1 = 0, sQ1 = 0;
    ushort_t* myT = tile[wid];

    for (int t = blockIdx.x * (BLOCK / 64) + wid; t < NTILES; t += WAVES) {
        const size_t rb = (size_t)t * 16;
        const short8 ha = *(const short8*)(h_in + (rb + m) * 32 + q * 8);  // A-layout, bf16
        float tf[8];
        #pragma unroll
        for (int j = 0; j < 8; ++j)
            tf[j] = silu_f(a1k[j] * bf2f(((const unsigned short*)&ha)[j]) + c1k[j]);
        const short8 ta = pack8(tf);
        const f32x4 z = {0.f, 0.f, 0.f, 0.f};
        f32x4 r0 = mfma16(ta, W10, z);
        f32x4 r1 = mfma16(ta, W11, z);
        float uf0[4], uf1[4];
        #pragma unroll
        for (int r = 0; r < 4; ++r) {
            uf0[r] = silu_f(a2c0 * r0[r] + d2c0);
            uf1[r] = silu_f(a2c1 * r1[r] + d2c1);
        }
        // C-layout -> A-layout transpose through per-wave LDS tile (intra-wave, DS in-order)
        __builtin_amdgcn_wave_barrier();
        #pragma unroll
        for (int r = 0; r < 4; ++r) {
            myT[(q * 4 + r) * 32 + m]      = f2bf(uf0[r]);
            myT[(q * 4 + r) * 32 + m + 16] = f2bf(uf1[r]);
        }
        __builtin_amdgcn_wave_barrier();
        const short8 ua = *(const short8*)(myT + m * 32 + q * 8);
        f32x4 c0 = {b2c0, b2c0, b2c0, b2c0}, c1 = {b2c1, b2c1, b2c1, b2c1};
        c0 = mfma16(ha, F0, c0);  c1 = mfma16(ha, F1, c1);
        c0 = mfma16(ua, W20, c0); c1 = mfma16(ua, W21, c1);
        float hn0[4], hn1[4];
        #pragma unroll
        for (int r = 0; r < 4; ++r) { hn0[r] = silu_f(c0[r]); hn1[r] = silu_f(c1[r]); }
        __builtin_amdgcn_wave_barrier();
        #pragma unroll
        for (int r = 0; r < 4; ++r) {
            myT[(q * 4 + r) * 32 + m]      = f2bf(hn0[r]);
            myT[(q * 4 + r) * 32 + m + 16] = f2bf(hn1[r]);
        }
        __builtin_amdgcn_wave_barrier();
        if (!LAST) {
            #pragma unroll
            for (int r = 0; r < 4; ++r) {
                sS0 += hn0[r]; sQ0 += hn0[r] * hn0[r];
                sS1 += hn1[r]; sQ1 += hn1[r] * hn1[r];
            }
            const short8 hv = *(const short8*)(myT + lane * 8);
            *(short8*)(h_out + rb * 32 + lane * 8) = hv;
        } else {
            // head via MFMA: hn (A-layout from tile) @ head_w[32x10 pad 16] + head_b
            const short8 hna = *(const short8*)(myT + m * 32 + q * 8);
            f32x4 oc = {hbc, hbc, hbc, hbc};
            oc = mfma16(hna, HW, oc);
            if (m < 10) {
                #pragma unroll
                for (int r = 0; r < 4; ++r) out[(rb + q * 4 + r) * 10 + m] = oc[r];
            }
        }
        __builtin_amdgcn_wave_barrier();
    }
    if (!LAST)
        stats_reduce_c(sS0, sQ0, sS1, sQ1, sRed, sOut + (size_t)(blockIdx.x & (NREP - 1)) * 64, tid);
}

extern "C" void kernel_launch(void* const* d_in, const int* in_sizes, int n_in,
                              void* d_out, int out_size, void* d_ws, size_t ws_size,
                              hipStream_t stream)
{
    const float* x      = (const float*)d_in[0];
    const float* stem_w = (const float*)d_in[1];
    const float* stem_b = (const float*)d_in[2];
    const float* fno_wr = (const float*)d_in[3];
    const float* fno_wi = (const float*)d_in[4];
    const float* bn1_g  = (const float*)d_in[5];
    const float* bn1_b  = (const float*)d_in[6];
    const float* lin1_w = (const float*)d_in[7];
    const float* lin1_b = (const float*)d_in[8];
    const float* bn2_g  = (const float*)d_in[9];
    const float* bn2_b  = (const float*)d_in[10];
    const float* lin2_w = (const float*)d_in[11];
    const float* lin2_b = (const float*)d_in[12];
    const float* head_w = (const float*)d_in[13];
    const float* head_b = (const float*)d_in[14];

    // workspace: [ h (B*32 bf16, 128 MiB) | Fp (4*1024 f32) | stats (8 sets * 16 reps * 64 f64) ]
    ushort_t* h  = (ushort_t*)d_ws;
    float*    Fp = (float*)((char*)d_ws + (size_t)BATCH * 32 * sizeof(ushort_t));
    double*   st = (double*)((char*)d_ws + (size_t)BATCH * 32 * sizeof(ushort_t) + 16384);

    hipMemsetAsync(st, 0, (size_t)NSETS * NREP * 64 * sizeof(double), stream);
    setup_f_kernel<<<4, BLOCK, 0, stream>>>(fno_wr, fno_wi, Fp);
    stem_kernel<<<GRID, BLOCK, 0, stream>>>(x, stem_w, stem_b, h, st);

    for (int l = 0; l < 4; ++l) {
        double* sH = st + (size_t)(2 * l) * NREP * 64;
        double* sR = st + (size_t)(2 * l + 1) * NREP * 64;
        p1_kernel<<<GRID, BLOCK, 0, stream>>>(
            h, sH, sR,
            bn1_g + l * 32, bn1_b + l * 32, lin1_w + l * 1024, lin1_b + l * 32);
        if (l < 3) {
            double* sN = st + (size_t)(2 * l + 2) * NREP * 64;
            p2_kernel<false><<<GRID, BLOCK, 0, stream>>>(
                h, h, nullptr, sH, sR, sN,
                bn1_g + l * 32, bn1_b + l * 32, lin1_w + l * 1024, lin1_b + l * 32,
                bn2_g + l * 32, bn2_b + l * 32, lin2_w + l * 1024, lin2_b + l * 32,
                Fp + l * 1024, nullptr, nullptr);
        } else {
            p2_kernel<true><<<GRID, BLOCK, 0, stream>>>(
                h, nullptr, (float*)d_out, sH, sR, st,
                bn1_g + l * 32, bn1_b + l * 32, lin1_w + l * 1024, lin1_b + l * 32,
                bn2_g + l * 32, bn2_b + l * 32, lin2_w + l * 1024, lin2_b + l * 32,
                Fp + l * 1024, head_w, head_b);
        }
    }
}